// Round 3
// baseline (219.824 us; speedup 1.0000x reference)
//
#include <hip/hip_runtime.h>

// Problem constants (fixed by the reference)
#define BATCH 256
#define CDIM  2048
#define HW    49
#define KDIM  16
#define CHUNK 512      // C-range per block in kernel A
#define TILE  128      // C per LDS tile in kernel A

// ---------------------------------------------------------------------------
// Kernel A: partial P[hw][k] = sum over a 512-wide C chunk of fm[c][hw]*w[k][c]
// grid = BATCH*4, block = 256 (4 waves).
// Thread: hw = lane (0..63; 49..63 wasted), cs = wave id (wave-uniform via
// readfirstlane) -> each wave owns a 32-c slice per tile.
// fm: flat LDS tile, stride-1 conflict-free b32 reads.
// w : global scalar loads (uniform address -> s_load_dwordx4, K$-cached).
// acc[16] = 16 VGPRs -> no AGPR spill.
// ---------------------------------------------------------------------------
__global__ __launch_bounds__(256) void pconv_kernel(
    const float* __restrict__ fm, const float* __restrict__ w16,
    float* __restrict__ Ppart)
{
    __shared__ __align__(16) float fm_t[6304];  // TILE*HW=6272 + pad (hw reads up to 63)

    const int tid = threadIdx.x;
    const int b   = blockIdx.x >> 2;
    const int q   = blockIdx.x & 3;
    const int hw  = tid & 63;
    const int wv  = __builtin_amdgcn_readfirstlane(tid >> 6);  // 0..3, uniform

    float acc[16];
    #pragma unroll
    for (int k = 0; k < 16; ++k) acc[k] = 0.f;

    const float* fmb = fm + (size_t)b * CDIM * HW;

    for (int tile = 0; tile < 4; ++tile) {
        const int ct = q * CHUNK + tile * TILE;
        __syncthreads();
        // --- stage fm tile FLAT: 1568 float4, fully coalesced, no scatter ---
        const float4* src = (const float4*)(fmb + ct * HW);
        float4* dst = (float4*)fm_t;
        #pragma unroll
        for (int it = 0; it < 6; ++it) dst[it * 256 + tid] = src[it * 256 + tid];
        if (tid < 32) dst[1536 + tid] = src[1536 + tid];
        __syncthreads();

        // --- compute: 32 cc per wave; fm b32 stride-1, w scalar dwordx4 ---
        const float* wbase = w16 + ct + wv * 32;   // uniform
        #pragma unroll 2
        for (int j4 = 0; j4 < 8; ++j4) {
            const int cc = wv * 32 + j4 * 4;
            float f0 = fm_t[(cc + 0) * HW + hw];
            float f1 = fm_t[(cc + 1) * HW + hw];
            float f2 = fm_t[(cc + 2) * HW + hw];
            float f3 = fm_t[(cc + 3) * HW + hw];
            #pragma unroll
            for (int k = 0; k < 16; ++k) {
                const float4 wq = *(const float4*)(wbase + k * CDIM + j4 * 4);
                acc[k] += wq.x * f0 + wq.y * f1 + wq.z * f2 + wq.w * f3;
            }
        }
    }

    // --- reduce the 4 wave-slices via LDS (aliases fm_t; stride-17 rows,
    //     conflict-free b32), output layout Ppart[block][hw*16+k] ---
    __syncthreads();
    float* red = fm_t;   // needs 4*64*17 = 4352 <= 6304
    #pragma unroll
    for (int k = 0; k < 16; ++k) red[wv * 1088 + hw * 17 + k] = acc[k];
    __syncthreads();

    const int e = tid * 4;
    if (e < 784) {       // 784 = 49*16 entries, [hw][k] flat
        float4 o;
        #pragma unroll
        for (int j = 0; j < 4; ++j) {
            const int ee = e + j, hh = ee >> 4, kk = ee & 15;
            ((float*)&o)[j] = red[hh * 17 + kk] + red[1088 + hh * 17 + kk]
                            + red[2176 + hh * 17 + kk] + red[3264 + hh * 17 + kk];
        }
        *(float4*)(Ppart + (size_t)blockIdx.x * 784 + e) = o;
    }
}

// ---------------------------------------------------------------------------
// Kernel A2: Pbn[b][hw*16+k] = BN(sum of 4 chunk-partials) / 49
// grid = BATCH, block = 256. Tiny: reads 3.2 MB, writes 0.8 MB (L2-resident).
// ---------------------------------------------------------------------------
__global__ __launch_bounds__(256) void preduce_kernel(
    const float* __restrict__ Ppart,
    const float* __restrict__ gamma, const float* __restrict__ beta,
    const float* __restrict__ mean, const float* __restrict__ var,
    float* __restrict__ Pbn)
{
    const int b = blockIdx.x;
    const float* pp = Ppart + (size_t)b * 4 * 784;
    for (int p = threadIdx.x; p < 784; p += 256) {
        float s = pp[p] + pp[p + 784] + pp[p + 1568] + pp[p + 2352];
        const int kk = p & 15;
        float inv   = gamma[kk] * rsqrtf(var[kk] + 1e-5f);
        float shift = beta[kk] - mean[kk] * inv;
        Pbn[(size_t)b * 784 + p] = (s * inv + shift) * (1.0f / 49.0f);
    }
}

// ---------------------------------------------------------------------------
// Kernel B: out[b][k][c] = sum_hw Pbn[b][hw][k] * fm[b][c][hw]
// grid = BATCH*8, block = 256. Thread t owns c = (blockIdx&7)*256 + t.
// fm staged flat in LDS (b128 in, stride-49 b32 out: gcd(49,32)=1 -> free).
// P read from global with uniform addresses -> s_load_dwordx4 (scalar pipe,
// 3 KB/b slice stays hot in K$) -> near-zero LDS/VMEM cost in the loop.
// ---------------------------------------------------------------------------
__global__ __launch_bounds__(256) void bp_kernel(
    const float* __restrict__ fm, const float* __restrict__ Pbn,
    float* __restrict__ out)
{
    __shared__ __align__(16) float fm_s[256 * HW];   // 50176 B

    const int tid = threadIdx.x;
    const int b   = blockIdx.x >> 3;
    const int c0  = (blockIdx.x & 7) * 256;

    // stage fm slice: 3136 float4, fully coalesced + contiguous
    const float4* src = (const float4*)(fm + ((size_t)b * CDIM + c0) * HW);
    float4* dst = (float4*)fm_s;
    #pragma unroll
    for (int i = 0; i < 12; ++i) dst[i * 256 + tid] = src[i * 256 + tid];
    if (tid < 64) dst[3072 + tid] = src[3072 + tid];
    __syncthreads();

    const float* Pb = Pbn + (size_t)b * 784;   // uniform base

    float acc[16];
    #pragma unroll
    for (int i = 0; i < 16; ++i) acc[i] = 0.f;

    const float* row = fm_s + tid * HW;
    #pragma unroll 7
    for (int hw = 0; hw < HW; ++hw) {
        float f = row[hw];
        const float4 p0 = *(const float4*)(Pb + hw * 16 + 0);   // uniform -> s_load
        const float4 p1 = *(const float4*)(Pb + hw * 16 + 4);
        const float4 p2 = *(const float4*)(Pb + hw * 16 + 8);
        const float4 p3 = *(const float4*)(Pb + hw * 16 + 12);
        acc[0]  += p0.x * f; acc[1]  += p0.y * f; acc[2]  += p0.z * f; acc[3]  += p0.w * f;
        acc[4]  += p1.x * f; acc[5]  += p1.y * f; acc[6]  += p1.z * f; acc[7]  += p1.w * f;
        acc[8]  += p2.x * f; acc[9]  += p2.y * f; acc[10] += p2.z * f; acc[11] += p2.w * f;
        acc[12] += p3.x * f; acc[13] += p3.y * f; acc[14] += p3.z * f; acc[15] += p3.w * f;
    }

    float* ob = out + (size_t)b * (KDIM * CDIM) + c0 + tid;
    #pragma unroll
    for (int kk = 0; kk < 16; ++kk) ob[kk * CDIM] = acc[kk];
}

extern "C" void kernel_launch(void* const* d_in, const int* in_sizes, int n_in,
                              void* d_out, int out_size, void* d_ws, size_t ws_size,
                              hipStream_t stream) {
    const float* fm    = (const float*)d_in[0];
    const float* w16   = (const float*)d_in[1];
    const float* gamma = (const float*)d_in[2];
    const float* beta  = (const float*)d_in[3];
    const float* mean  = (const float*)d_in[4];
    const float* var   = (const float*)d_in[5];
    float* out   = (float*)d_out;
    float* Ppart = (float*)d_ws;                    // 1024*784*4 = 3.2 MB
    float* Pbn   = Ppart + (size_t)1024 * 784;      // + 256*784*4 = 0.8 MB

    pconv_kernel<<<BATCH * 4, 256, 0, stream>>>(fm, w16, Ppart);
    preduce_kernel<<<BATCH, 256, 0, stream>>>(Ppart, gamma, beta, mean, var, Pbn);
    bp_kernel<<<BATCH * 8, 256, 0, stream>>>(fm, Pbn, out);
}